// Round 6
// baseline (371.200 us; speedup 1.0000x reference)
//
#include <hip/hip_runtime.h>
#include <stdint.h>
#include <stddef.h>

#define DEV __device__ __forceinline__

typedef _Float16 f16x8 __attribute__((ext_vector_type(8)));
typedef float    f32x4 __attribute__((ext_vector_type(4)));
typedef int      i32x4 __attribute__((ext_vector_type(4)));

#define K2E 1.44269504088896340736f
#define SC25 (25.0f * K2E)

DEV uint16_t f2h(float f) {
  _Float16 h = (_Float16)f;
  return __builtin_bit_cast(uint16_t, h);
}
DEV float h2f(uint16_t u) {
  return (float)__builtin_bit_cast(_Float16, u);
}
DEV f16x8 ldfrag(const uint16_t* p) {
  i32x4 v = *(const i32x4*)p;
  return __builtin_bit_cast(f16x8, v);
}
DEV f32x4 mfma16(f16x8 a, f16x8 b, f32x4 c) {
  return __builtin_amdgcn_mfma_f32_16x16x32_f16(a, b, c, 0, 0, 0);
}
// async global->LDS: each lane copies 16B; LDS dest = base + lane*16
DEV void gld_lds16(const uint16_t* g, uint16_t* l) {
  __builtin_amdgcn_global_load_lds(
      (__attribute__((address_space(1))) void*)g,
      (__attribute__((address_space(3))) void*)l, 16, 0, 0);
}

union U16x8 { uint16_t u[8]; i32x4 v; };

// ---------------- fused prep: casts + weight transposes ---------------------
__global__ __launch_bounds__(256) void prep_kernel(
    const float* __restrict__ x_cls, const float* __restrict__ x_reg,
    const float* __restrict__ W_cls, const float* __restrict__ W_reg,
    uint16_t* __restrict__ xc_b, uint16_t* __restrict__ xr_b,
    uint16_t* __restrict__ Wtc, uint16_t* __restrict__ Wtr) {
  __shared__ float tile[64][65];
  int b = blockIdx.x, tid = threadIdx.x;
  if (b < 2048) {
    const float* in = (b < 1024) ? x_cls : x_reg;
    uint16_t* outp = (b < 1024) ? xc_b : xr_b;
    int i = (b & 1023) * 256 + tid;
    float4 a = *(const float4*)(in + (size_t)i * 8);
    float4 c = *(const float4*)(in + (size_t)i * 8 + 4);
    U16x8 r;
    r.u[0] = f2h(a.x); r.u[1] = f2h(a.y); r.u[2] = f2h(a.z); r.u[3] = f2h(a.w);
    r.u[4] = f2h(c.x); r.u[5] = f2h(c.y); r.u[6] = f2h(c.z); r.u[7] = f2h(c.w);
    *(i32x4*)(outp + (size_t)i * 8) = r.v;
    return;
  }
  const float* W;
  uint16_t* Wt;
  int idx;
  if (b < 2816) { W = W_cls; Wt = Wtc; idx = b - 2048; }
  else          { W = W_reg; Wt = Wtr; idx = b - 2816; }
  int k0 = (idx & 15) * 64;
  int n0 = (idx >> 4) * 64;
#pragma unroll
  for (int i = 0; i < 16; ++i) {
    int flat = i * 256 + tid;
    int r = flat >> 6, c = flat & 63;
    tile[r][c] = W[(size_t)(k0 + r) * 3072 + n0 + c];
  }
  __syncthreads();
#pragma unroll
  for (int i = 0; i < 16; ++i) {
    int flat = i * 256 + tid;
    int r = flat >> 6, c = flat & 63;
    Wt[(size_t)(n0 + r) * 1024 + k0 + c] = f2h(tile[c][r]);
  }
}

// ---------------- fused QKV GEMM + l2norm + pack ----------------------------
// grid (16, 40): bm=row tile (128 n-rows), bn: <24 cls (tz=bn>>3: q/k/v, h=bn&7),
// else reg (b2=bn-24, tz=b2>>3: q/k, h=b2&7). 128-col tile == one (type,head),
// so the d=128 l2-norm is block-local. Epilogue LDS-stages f16 tiles for
// coalesced writes (incl. Vt transpose); x_ori f32 written direct from regs.
__global__ __launch_bounds__(256, 2) void gemm_qkv_norm_kernel(
    const uint16_t* __restrict__ xc, const uint16_t* __restrict__ Wtc,
    const uint16_t* __restrict__ xr, const uint16_t* __restrict__ Wtr,
    uint16_t* __restrict__ Qc, uint16_t* __restrict__ Kc,
    uint16_t* __restrict__ Qr, uint16_t* __restrict__ Kr,
    uint16_t* __restrict__ Vt, uint16_t* __restrict__ Vcat,
    float* __restrict__ out) {
  __shared__ __align__(16) uint16_t pool[128 * 136];  // 34816 B
  __shared__ float rowss[2][128];
  uint16_t* As = pool;
  uint16_t* Bs = pool + 8192;

  int bm = blockIdx.x, bn = blockIdx.y;
  int n0 = bm * 128;
  const uint16_t* A;
  const uint16_t* Brow;
  int tz, h, iscls;
  if (bn < 24) {
    A = xc; Brow = Wtc + (size_t)(bn * 128) * 1024;
    tz = bn >> 3; h = bn & 7; iscls = 1;
  } else {
    int b2 = bn - 24;
    A = xr; Brow = Wtr + (size_t)(b2 * 128) * 1024;
    tz = b2 >> 3; h = b2 & 7; iscls = 0;
  }
  int tid = threadIdx.x;
  int w = tid >> 6, lane = tid & 63, quad = lane >> 4, l15 = lane & 15;
  int wm = (w >> 1) * 64, wn = (w & 1) * 64;
  const uint16_t* Arow = A + (size_t)n0 * 1024;
  f32x4 acc[4][4];
  f32x4 zero = {0.f, 0.f, 0.f, 0.f};
#pragma unroll
  for (int i = 0; i < 4; ++i)
#pragma unroll
    for (int j = 0; j < 4; ++j) acc[i][j] = zero;
  int rl = lane >> 3, cl = lane & 7;
  int sw = l15 & 7;
  for (int k0 = 0; k0 < 1024; k0 += 64) {
    __syncthreads();
#pragma unroll
    for (int t = 0; t < 4; ++t) {
      int r0 = w * 32 + t * 8;
      gld_lds16(Arow + (size_t)(r0 + rl) * 1024 + k0 + ((cl ^ rl) << 3), As + r0 * 64);
      gld_lds16(Brow + (size_t)(r0 + rl) * 1024 + k0 + ((cl ^ rl) << 3), Bs + r0 * 64);
    }
    __syncthreads();
#pragma unroll
    for (int ks = 0; ks < 2; ++ks) {
      f16x8 af[4], bf[4];
#pragma unroll
      for (int mt = 0; mt < 4; ++mt)
        af[mt] = ldfrag(As + (wm + mt * 16 + l15) * 64 + ((((ks << 2) + quad) ^ sw) << 3));
#pragma unroll
      for (int nt = 0; nt < 4; ++nt)
        bf[nt] = ldfrag(Bs + (wn + nt * 16 + l15) * 64 + ((((ks << 2) + quad) ^ sw) << 3));
#pragma unroll
      for (int mt = 0; mt < 4; ++mt)
#pragma unroll
        for (int nt = 0; nt < 4; ++nt)
          acc[mt][nt] = mfma16(af[mt], bf[nt], acc[mt][nt]);
    }
  }
  __syncthreads();  // (a) all frag reads of pool done

  // per-row sumsq: in-lane over nt, cross-lane over l15, cross-wave via LDS
  float ss[4][4];
#pragma unroll
  for (int mt = 0; mt < 4; ++mt)
#pragma unroll
    for (int r = 0; r < 4; ++r) {
      float s = 0.f;
#pragma unroll
      for (int nt = 0; nt < 4; ++nt) s += acc[mt][nt][r] * acc[mt][nt][r];
      s += __shfl_xor(s, 1);
      s += __shfl_xor(s, 2);
      s += __shfl_xor(s, 4);
      s += __shfl_xor(s, 8);
      ss[mt][r] = s;
    }
  int half = w & 1;
  if (l15 == 0) {
#pragma unroll
    for (int mt = 0; mt < 4; ++mt)
#pragma unroll
      for (int r = 0; r < 4; ++r)
        rowss[half][wm + mt * 16 + quad * 4 + r] = ss[mt][r];
  }
  __syncthreads();  // (b) rowss visible
  float rn[4][4];
#pragma unroll
  for (int mt = 0; mt < 4; ++mt)
#pragma unroll
    for (int r = 0; r < 4; ++r) {
      int row = wm + mt * 16 + quad * 4 + r;
      rn[mt][r] = rsqrtf(rowss[0][row] + rowss[1][row]);
    }

  // normalized f16 -> LDS tile (stride 136, 16B-aligned rows)
  uint16_t* tile = pool;
#pragma unroll
  for (int mt = 0; mt < 4; ++mt)
#pragma unroll
    for (int nt = 0; nt < 4; ++nt)
#pragma unroll
      for (int r = 0; r < 4; ++r) {
        int row = wm + mt * 16 + quad * 4 + r;
        int col = wn + nt * 16 + l15;
        tile[row * 136 + col] = f2h(acc[mt][nt][r] * rn[mt][r]);
      }
  if (tz == 2) {  // x_ori f32 direct (64B-chunk coalescing)
#pragma unroll
    for (int mt = 0; mt < 4; ++mt)
#pragma unroll
      for (int nt = 0; nt < 4; ++nt)
#pragma unroll
        for (int r = 0; r < 4; ++r) {
          int row = wm + mt * 16 + quad * 4 + r;
          int col = wn + nt * 16 + l15;
          out[(size_t)(n0 + row) * 2048 + 1024 + h * 128 + col] = acc[mt][nt][r];
        }
  }
  __syncthreads();  // (c) tile visible

  // coalesced store of normalized tile
  {
    int trow = tid >> 1, tco = (tid & 1) << 6;
    const uint16_t* src = tile + trow * 136 + tco;
    uint16_t* dst;
    size_t base;
    if (tz == 0) { dst = iscls ? Qc : Qr; base = ((size_t)h * 2048 + n0 + trow) * 128 + tco; }
    else if (tz == 1) { dst = iscls ? Kc : Kr; base = ((size_t)h * 2048 + n0 + trow) * 128 + tco; }
    else { dst = Vcat; base = (size_t)(n0 + trow) * 1024 + h * 128 + tco; }
#pragma unroll
    for (int j = 0; j < 8; ++j)
      *(i32x4*)(dst + base + j * 8) = *(const i32x4*)(src + j * 8);
  }

  if (tz == 2) {  // raw V transposed -> Vt
    __syncthreads();  // (d) Vcat pass done reading tile
#pragma unroll
    for (int mt = 0; mt < 4; ++mt)
#pragma unroll
      for (int nt = 0; nt < 4; ++nt)
#pragma unroll
        for (int r = 0; r < 4; ++r) {
          int row = wm + mt * 16 + quad * 4 + r;
          int col = wn + nt * 16 + l15;
          tile[col * 136 + row] = f2h(acc[mt][nt][r]);
        }
    __syncthreads();  // (e)
    int trow = tid >> 1, tco = (tid & 1) << 6;
    size_t base = ((size_t)h * 128 + trow) * 2048 + n0 + tco;
#pragma unroll
    for (int j = 0; j < 8; ++j)
      *(i32x4*)(Vt + base + j * 8) = *(const i32x4*)(tile + trow * 136 + tco + j * 8);
  }
}

// ---------------- mask GEMM: (Vcat.Vcat^T > 6) -> u8 ------------------------
__global__ __launch_bounds__(256, 2) void gemm_mask_kernel(
    const uint16_t* __restrict__ Vcat, uint8_t* __restrict__ mask) {
  __shared__ __align__(16) uint16_t As[128 * 64];
  __shared__ __align__(16) uint16_t Bs[128 * 64];
  int tid = threadIdx.x;
  int w = tid >> 6, lane = tid & 63, quad = lane >> 4, l15 = lane & 15;
  int wm = (w >> 1) * 64, wn = (w & 1) * 64;
  int bm = blockIdx.x, bn = blockIdx.y;
  const uint16_t* Arow = Vcat + (size_t)(bm * 128) * 1024;
  const uint16_t* Brow = Vcat + (size_t)(bn * 128) * 1024;
  f32x4 acc[4][4];
  f32x4 zero = {0.f, 0.f, 0.f, 0.f};
#pragma unroll
  for (int i = 0; i < 4; ++i)
#pragma unroll
    for (int j = 0; j < 4; ++j) acc[i][j] = zero;
  int rl = lane >> 3, cl = lane & 7;
  int sw = l15 & 7;
  for (int k0 = 0; k0 < 1024; k0 += 64) {
    __syncthreads();
#pragma unroll
    for (int t = 0; t < 4; ++t) {
      int r0 = w * 32 + t * 8;
      gld_lds16(Arow + (size_t)(r0 + rl) * 1024 + k0 + ((cl ^ rl) << 3), As + r0 * 64);
      gld_lds16(Brow + (size_t)(r0 + rl) * 1024 + k0 + ((cl ^ rl) << 3), Bs + r0 * 64);
    }
    __syncthreads();
#pragma unroll
    for (int ks = 0; ks < 2; ++ks) {
      f16x8 af[4], bf[4];
#pragma unroll
      for (int mt = 0; mt < 4; ++mt)
        af[mt] = ldfrag(As + (wm + mt * 16 + l15) * 64 + ((((ks << 2) + quad) ^ sw) << 3));
#pragma unroll
      for (int nt = 0; nt < 4; ++nt)
        bf[nt] = ldfrag(Bs + (wn + nt * 16 + l15) * 64 + ((((ks << 2) + quad) ^ sw) << 3));
#pragma unroll
      for (int mt = 0; mt < 4; ++mt)
#pragma unroll
        for (int nt = 0; nt < 4; ++nt)
          acc[mt][nt] = mfma16(af[mt], bf[nt], acc[mt][nt]);
    }
  }
#pragma unroll
  for (int mt = 0; mt < 4; ++mt)
#pragma unroll
    for (int nt = 0; nt < 4; ++nt) {
      int row = bm * 128 + wm + mt * 16 + quad * 4;
      int col = bn * 128 + wn + nt * 16 + l15;
#pragma unroll
      for (int r = 0; r < 4; ++r)
        mask[(size_t)(row + r) * 2048 + col] = (acc[mt][nt][r] > 6.0f) ? 1 : 0;
    }
}

// ---------------- flash attention: 8-wave blocks, shared K/V staging --------
// grid 512 x 512 threads: h=bx&7, s=(bx>>3)&1 (m-split), q64=bx>>4 (32).
// Waves 0-3 = cls rows wq*16, waves 4-7 = reg. LDS 64KB exactly -> 2 blk/CU.
__global__ __launch_bounds__(512, 4) void attn_kernel(
    const uint16_t* __restrict__ Qc, const uint16_t* __restrict__ Kc,
    const uint16_t* __restrict__ Qr, const uint16_t* __restrict__ Kr,
    const uint16_t* __restrict__ Vt,
    const float* __restrict__ cls_score, const float* __restrict__ fg_score,
    uint16_t* __restrict__ Opart, float* __restrict__ Mpart,
    float* __restrict__ Lpart) {
  __shared__ __align__(16) uint16_t sKc[64 * 128];   // 16 KB
  __shared__ __align__(16) uint16_t sKr[64 * 128];   // 16 KB
  __shared__ __align__(16) uint16_t sVt[128 * 64];   // 16 KB
  __shared__ __align__(16) uint16_t sP[8 * 1024];    // 16 KB (per-wave 16x64)

  int bx = blockIdx.x;
  int h = bx & 7;
  int s_ = (bx >> 3) & 1;
  int q64 = bx >> 4;
  int tid = threadIdx.x, w = tid >> 6, lane = tid & 63;
  int quad = lane >> 4, l15 = lane & 15;
  int p = w >> 2, wq = w & 3;
  int qbase = q64 * 64 + wq * 16;
  int mstart = s_ * 1024;
  uint16_t* Pb = sP + w * 1024;

  const uint16_t* Qp = p ? Qr : Qc;
  const float* score = p ? fg_score : cls_score;
  const uint16_t* Khc = Kc + (size_t)h * 2048 * 128;
  const uint16_t* Khr = Kr + (size_t)h * 2048 * 128;
  const uint16_t* Vh = Vt + (size_t)h * 128 * 2048;

  f16x8 qf[4];
  const uint16_t* qp = Qp + ((size_t)h * 2048 + qbase + l15) * 128;
#pragma unroll
  for (int ks = 0; ks < 4; ++ks) qf[ks] = ldfrag(qp + ks * 32 + quad * 8);

  float sq[4];
#pragma unroll
  for (int r = 0; r < 4; ++r) sq[r] = score[qbase + quad * 4 + r] - 0.1f;

  float M[4], Lacc[4];
  f32x4 O[8];
  f32x4 zero = {0.f, 0.f, 0.f, 0.f};
#pragma unroll
  for (int i = 0; i < 8; ++i) O[i] = zero;
#pragma unroll
  for (int r = 0; r < 4; ++r) { M[r] = -3.0e38f; Lacc[r] = 0.f; }

  int krl = lane >> 4, kcl = lane & 15;  // K stage: 4 rows x 16 segs per call
  int vrl = lane >> 3, vcl = lane & 7;   // V stage: 8 rows x 8 segs per call
  int xk = l15 & 7;

  for (int it = 0; it < 16; ++it) {
    int m0 = mstart + it * 64;
    __syncthreads();
    if (w < 4) {
#pragma unroll
      for (int t = 0; t < 4; ++t) {
        int r0 = w * 16 + t * 4;
        int key = (r0 + krl) & 7;
        gld_lds16(Khc + (size_t)(m0 + r0 + krl) * 128 + ((kcl ^ key) << 3),
                  sKc + r0 * 128);
      }
    } else {
#pragma unroll
      for (int t = 0; t < 4; ++t) {
        int r0 = (w - 4) * 16 + t * 4;
        int key = (r0 + krl) & 7;
        gld_lds16(Khr + (size_t)(m0 + r0 + krl) * 128 + ((kcl ^ key) << 3),
                  sKr + r0 * 128);
      }
    }
#pragma unroll
    for (int t = 0; t < 2; ++t) {
      int d0 = w * 16 + t * 8;
      gld_lds16(Vh + (size_t)(d0 + vrl) * 2048 + m0 + ((vcl ^ vrl) << 3),
                sVt + d0 * 64);
    }
    __syncthreads();

    const uint16_t* sK = p ? sKr : sKc;
    f32x4 S[4];
#pragma unroll
    for (int mt = 0; mt < 4; ++mt) S[mt] = zero;
#pragma unroll
    for (int ks = 0; ks < 4; ++ks)
#pragma unroll
      for (int mt = 0; mt < 4; ++mt) {
        f16x8 b = ldfrag(sK + (mt * 16 + l15) * 128 + (((ks * 4 + quad) ^ xk) << 3));
        S[mt] = mfma16(qf[ks], b, S[mt]);
      }

    float l2[4][4];
#pragma unroll
    for (int mt = 0; mt < 4; ++mt) {
      float scm = score[m0 + mt * 16 + l15];
      float sc2 = scm * SC25;
#pragma unroll
      for (int r = 0; r < 4; ++r)
        l2[mt][r] = (scm > sq[r]) ? S[mt][r] * sc2 : 0.0f;
    }
    float Mnew[4], alpha[4];
#pragma unroll
    for (int r = 0; r < 4; ++r) {
      float v = fmaxf(fmaxf(l2[0][r], l2[1][r]), fmaxf(l2[2][r], l2[3][r]));
      v = fmaxf(v, __shfl_xor(v, 1));
      v = fmaxf(v, __shfl_xor(v, 2));
      v = fmaxf(v, __shfl_xor(v, 4));
      v = fmaxf(v, __shfl_xor(v, 8));
      Mnew[r] = fmaxf(M[r], v);
      alpha[r] = __builtin_amdgcn_exp2f(M[r] - Mnew[r]);
      M[r] = Mnew[r];
    }
#pragma unroll
    for (int r = 0; r < 4; ++r) {
      float ssum = 0.f;
#pragma unroll
      for (int mt = 0; mt < 4; ++mt) {
        float pe = __builtin_amdgcn_exp2f(l2[mt][r] - Mnew[r]);
        l2[mt][r] = pe;
        ssum += pe;
      }
      Lacc[r] = Lacc[r] * alpha[r] + ssum;
    }
#pragma unroll
    for (int dt = 0; dt < 8; ++dt)
#pragma unroll
      for (int r = 0; r < 4; ++r) O[dt][r] *= alpha[r];

#pragma unroll
    for (int mt = 0; mt < 4; ++mt) {
      int seg = mt * 2 + (l15 >> 3);
#pragma unroll
      for (int r = 0; r < 4; ++r) {
        int row = quad * 4 + r;
        Pb[row * 64 + ((seg ^ (row & 7)) << 3) + (l15 & 7)] = f2h(l2[mt][r]);
      }
    }
#pragma unroll
    for (int ks2 = 0; ks2 < 2; ++ks2) {
      f16x8 a = ldfrag(Pb + l15 * 64 + (((ks2 * 4 + quad) ^ xk) << 3));
#pragma unroll
      for (int dt = 0; dt < 8; ++dt) {
        f16x8 b = ldfrag(sVt + (dt * 16 + l15) * 64 + (((ks2 * 4 + quad) ^ xk) << 3));
        O[dt] = mfma16(a, b, O[dt]);
      }
    }
  }

  float L[4];
#pragma unroll
  for (int r = 0; r < 4; ++r) {
    float s = Lacc[r];
    s += __shfl_xor(s, 1);
    s += __shfl_xor(s, 2);
    s += __shfl_xor(s, 4);
    s += __shfl_xor(s, 8);
    L[r] = s;
  }
  int plane = p * 2 + s_;
  uint16_t* Op = Opart + (size_t)plane * 2097152;
#pragma unroll
  for (int dt = 0; dt < 8; ++dt)
#pragma unroll
    for (int r = 0; r < 4; ++r)
      Op[(size_t)(qbase + quad * 4 + r) * 1024 + h * 128 + dt * 16 + l15] =
          f2h(O[dt][r]);
  if (l15 == 0) {
#pragma unroll
    for (int r = 0; r < 4; ++r) {
      int qrow = qbase + quad * 4 + r;
      Mpart[((size_t)plane * 8 + h) * 2048 + qrow] = M[r];
      Lpart[((size_t)plane * 8 + h) * 2048 + qrow] = L[r];
    }
  }
}

// ---------------- fused combine + sim_round2 --------------------------------
__global__ __launch_bounds__(256) void combine_sim_kernel(
    const uint16_t* __restrict__ Opart, const float* __restrict__ Mpart,
    const float* __restrict__ Lpart, const uint8_t* __restrict__ mask,
    const uint16_t* __restrict__ Qc, const uint16_t* __restrict__ Kc,
    const uint16_t* __restrict__ Qr, const uint16_t* __restrict__ Kr,
    const float* __restrict__ cls_score, const float* __restrict__ fg_score,
    float* __restrict__ out, float* __restrict__ simout) {
  int n = blockIdx.x;
  int t = threadIdx.x;
  __shared__ float sM[2][8], sL[2][8];
  __shared__ float red[4];
  __shared__ float s_inv;
  if (t < 16) {
    int p = t >> 3, hh = t & 7;
    size_t i1 = ((size_t)(p * 2 + 0) * 8 + hh) * 2048 + n;
    size_t i2 = ((size_t)(p * 2 + 1) * 8 + hh) * 2048 + n;
    float M1 = Mpart[i1], M2 = Mpart[i2];
    float L1 = Lpart[i1], L2 = Lpart[i2];
    float Mx = fmaxf(M1, M2);
    float Lx = L1 * __builtin_amdgcn_exp2f(M1 - Mx) +
               L2 * __builtin_amdgcn_exp2f(M2 - Mx);
    sM[p][hh] = Mx;
    sL[p][hh] = Lx;
  }
  __syncthreads();

  // combine partials -> out row n (first 1024 cols)
  {
    int col = t * 4;
    int h = col >> 7;
    float res[4] = {0.f, 0.f, 0.f, 0.f};
#pragma unroll
    for (int p = 0; p < 2; ++p) {
      size_t i1 = ((size_t)(p * 2 + 0) * 8 + h) * 2048 + n;
      size_t i2 = ((size_t)(p * 2 + 1) * 8 + h) * 2048 + n;
      float Mx = sM[p][h];
      float iLx = 0.5f / sL[p][h];
      float f1 = __builtin_amdgcn_exp2f(Mpart[i1] - Mx) * iLx;
      float f2 = __builtin_amdgcn_exp2f(Mpart[i2] - Mx) * iLx;
      const uint16_t* O1 = Opart + (size_t)(p * 2 + 0) * 2097152 + (size_t)n * 1024 + col;
      const uint16_t* O2 = Opart + (size_t)(p * 2 + 1) * 2097152 + (size_t)n * 1024 + col;
      ushort4 a1 = *(const ushort4*)O1;
      ushort4 a2 = *(const ushort4*)O2;
      res[0] += h2f(a1.x) * f1 + h2f(a2.x) * f2;
      res[1] += h2f(a1.y) * f1 + h2f(a2.y) * f2;
      res[2] += h2f(a1.z) * f1 + h2f(a2.z) * f2;
      res[3] += h2f(a1.w) * f1 + h2f(a2.w) * f2;
    }
    float4 r4 = {res[0], res[1], res[2], res[3]};
    *(float4*)(out + (size_t)n * 2048 + col) = r4;
  }

  // sim_round2: masked-restricted softmax (thread t owns m = t*8 .. t*8+7)
  int mbase = t * 8;
  union { unsigned long long v; uint8_t b[8]; } mk;
  mk.v = *(const unsigned long long*)(mask + (size_t)n * 2048 + mbase);
  float e[8];
  float psum = 0.f;
  float cs_n = cls_score[n] - 0.1f, fs_n = fg_score[n] - 0.1f;
#pragma unroll
  for (int i = 0; i < 8; ++i) {
    int m = mbase + i;
    float val = 0.f;
    if (mk.b[i]) {
      float s = 0.f;
      float c2 = SC25 * cls_score[m];
      float r2 = SC25 * fg_score[m];
      float mc = (cls_score[m] > cs_n) ? 1.f : 0.f;
      float mr = (fg_score[m] > fs_n) ? 1.f : 0.f;
      for (int hh = 0; hh < 8; ++hh) {
        const uint16_t* qc = Qc + ((size_t)hh * 2048 + n) * 128;
        const uint16_t* kc = Kc + ((size_t)hh * 2048 + m) * 128;
        const uint16_t* qr = Qr + ((size_t)hh * 2048 + n) * 128;
        const uint16_t* kr = Kr + ((size_t)hh * 2048 + m) * 128;
        float dc = 0.f, dr = 0.f;
        for (int d = 0; d < 128; ++d) {
          dc += h2f(qc[d]) * h2f(kc[d]);
          dr += h2f(qr[d]) * h2f(kr[d]);
        }
        float lc = dc * c2 * mc;
        float lr = dr * r2 * mr;
        float ac = __builtin_amdgcn_exp2f(lc - sM[0][hh]) / sL[0][hh];
        float ar = __builtin_amdgcn_exp2f(lr - sM[1][hh]) / sL[1][hh];
        s += ac + ar;
      }
      s *= (1.0f / 16.0f);
      val = __builtin_amdgcn_exp2f(s * K2E);  // e^s
    }
    e[i] = val;
    psum += val;
  }
  for (int off = 1; off < 64; off <<= 1) psum += __shfl_xor(psum, off);
  if ((t & 63) == 0) red[t >> 6] = psum;
  __syncthreads();
  if (t == 0) s_inv = 1.0f / (red[0] + red[1] + red[2] + red[3]);
  __syncthreads();
  float inv = s_inv;
  float4 r0 = {e[0] * inv, e[1] * inv, e[2] * inv, e[3] * inv};
  float4 r1 = {e[4] * inv, e[5] * inv, e[6] * inv, e[7] * inv};
  *(float4*)(simout + (size_t)n * 2048 + mbase) = r0;
  *(float4*)(simout + (size_t)n * 2048 + mbase + 4) = r1;
}

// ---------------- host launch ------------------------------------------------
extern "C" void kernel_launch(void* const* d_in, const int* in_sizes, int n_in,
                              void* d_out, int out_size, void* d_ws, size_t ws_size,
                              hipStream_t stream) {
  const float* x_cls = (const float*)d_in[0];
  const float* x_reg = (const float*)d_in[1];
  const float* cls_score = (const float*)d_in[2];
  const float* fg_score = (const float*)d_in[3];
  const float* W_cls = (const float*)d_in[4];
  const float* W_reg = (const float*)d_in[5];
  float* out = (float*)d_out;
  char* ws = (char*)d_ws;

  const size_t OFF_XC   = 0;
  const size_t OFF_XR   = OFF_XC + 4194304;
  const size_t OFF_WTC  = OFF_XR + 4194304;
  const size_t OFF_WTR  = OFF_WTC + 6291456;
  const size_t OFF_QC   = OFF_WTR + 4194304;
  const size_t OFF_KC   = OFF_QC + 4194304;
  const size_t OFF_QR   = OFF_KC + 4194304;
  const size_t OFF_KR   = OFF_QR + 4194304;
  const size_t OFF_VT   = OFF_KR + 4194304;
  const size_t OFF_VCAT = OFF_VT + 4194304;
  const size_t OFF_OP   = OFF_VCAT + 4194304;   // 16 MB
  const size_t OFF_MP   = OFF_OP + 16777216;    // 256 KB
  const size_t OFF_LP   = OFF_MP + 262144;      // 256 KB
  const size_t OFF_MASK = OFF_LP + 262144;      // 4 MB

  uint16_t* xc_b = (uint16_t*)(ws + OFF_XC);
  uint16_t* xr_b = (uint16_t*)(ws + OFF_XR);
  uint16_t* Wtc  = (uint16_t*)(ws + OFF_WTC);
  uint16_t* Wtr  = (uint16_t*)(ws + OFF_WTR);
  uint16_t* Qc   = (uint16_t*)(ws + OFF_QC);
  uint16_t* Kc   = (uint16_t*)(ws + OFF_KC);
  uint16_t* Qr   = (uint16_t*)(ws + OFF_QR);
  uint16_t* Kr   = (uint16_t*)(ws + OFF_KR);
  uint16_t* Vt   = (uint16_t*)(ws + OFF_VT);
  uint16_t* Vcat = (uint16_t*)(ws + OFF_VCAT);
  uint16_t* Opart = (uint16_t*)(ws + OFF_OP);
  float* Mpart   = (float*)(ws + OFF_MP);
  float* Lpart   = (float*)(ws + OFF_LP);
  uint8_t* mask  = (uint8_t*)(ws + OFF_MASK);

  prep_kernel<<<3328, 256, 0, stream>>>(x_cls, x_reg, W_cls, W_reg,
                                        xc_b, xr_b, Wtc, Wtr);
  gemm_qkv_norm_kernel<<<dim3(16, 40), 256, 0, stream>>>(
      xc_b, Wtc, xr_b, Wtr, Qc, Kc, Qr, Kr, Vt, Vcat, out);
  gemm_mask_kernel<<<dim3(16, 16), 256, 0, stream>>>(Vcat, mask);
  attn_kernel<<<512, 512, 0, stream>>>(Qc, Kc, Qr, Kr, Vt, cls_score, fg_score,
                                       Opart, Mpart, Lpart);
  combine_sim_kernel<<<2048, 256, 0, stream>>>(Opart, Mpart, Lpart, mask,
                                               Qc, Kc, Qr, Kr, cls_score,
                                               fg_score, out, out + 4194304);
}

// Round 7
// 294.196 us; speedup vs baseline: 1.2617x; 1.2617x over previous
//
#include <hip/hip_runtime.h>
#include <stdint.h>
#include <stddef.h>

#define DEV __device__ __forceinline__

typedef _Float16 f16x8 __attribute__((ext_vector_type(8)));
typedef float    f32x4 __attribute__((ext_vector_type(4)));
typedef int      i32x4 __attribute__((ext_vector_type(4)));

#define K2E 1.44269504088896340736f
#define SC25 (25.0f * K2E)

DEV uint16_t f2h(float f) {
  _Float16 h = (_Float16)f;
  return __builtin_bit_cast(uint16_t, h);
}
DEV float h2f(uint16_t u) {
  return (float)__builtin_bit_cast(_Float16, u);
}
DEV f16x8 ldfrag(const uint16_t* p) {
  i32x4 v = *(const i32x4*)p;
  return __builtin_bit_cast(f16x8, v);
}
DEV f32x4 mfma16(f16x8 a, f16x8 b, f32x4 c) {
  return __builtin_amdgcn_mfma_f32_16x16x32_f16(a, b, c, 0, 0, 0);
}
// async global->LDS: each lane copies 16B; LDS dest = base + lane*16
DEV void gld_lds16(const uint16_t* g, uint16_t* l) {
  __builtin_amdgcn_global_load_lds(
      (__attribute__((address_space(1))) void*)g,
      (__attribute__((address_space(3))) void*)l, 16, 0, 0);
}

union U16x8 { uint16_t u[8]; i32x4 v; };

// ---------------- fused prep: casts + weight transposes ---------------------
__global__ __launch_bounds__(256) void prep_kernel(
    const float* __restrict__ x_cls, const float* __restrict__ x_reg,
    const float* __restrict__ W_cls, const float* __restrict__ W_reg,
    uint16_t* __restrict__ xc_b, uint16_t* __restrict__ xr_b,
    uint16_t* __restrict__ Wtc, uint16_t* __restrict__ Wtr) {
  __shared__ float tile[64][65];
  int b = blockIdx.x, tid = threadIdx.x;
  if (b < 2048) {
    const float* in = (b < 1024) ? x_cls : x_reg;
    uint16_t* outp = (b < 1024) ? xc_b : xr_b;
    int i = (b & 1023) * 256 + tid;
    float4 a = *(const float4*)(in + (size_t)i * 8);
    float4 c = *(const float4*)(in + (size_t)i * 8 + 4);
    U16x8 r;
    r.u[0] = f2h(a.x); r.u[1] = f2h(a.y); r.u[2] = f2h(a.z); r.u[3] = f2h(a.w);
    r.u[4] = f2h(c.x); r.u[5] = f2h(c.y); r.u[6] = f2h(c.z); r.u[7] = f2h(c.w);
    *(i32x4*)(outp + (size_t)i * 8) = r.v;
    return;
  }
  const float* W;
  uint16_t* Wt;
  int idx;
  if (b < 2816) { W = W_cls; Wt = Wtc; idx = b - 2048; }
  else          { W = W_reg; Wt = Wtr; idx = b - 2816; }
  int k0 = (idx & 15) * 64;
  int n0 = (idx >> 4) * 64;
#pragma unroll
  for (int i = 0; i < 16; ++i) {
    int flat = i * 256 + tid;
    int r = flat >> 6, c = flat & 63;
    tile[r][c] = W[(size_t)(k0 + r) * 3072 + n0 + c];
  }
  __syncthreads();
#pragma unroll
  for (int i = 0; i < 16; ++i) {
    int flat = i * 256 + tid;
    int r = flat >> 6, c = flat & 63;
    Wt[(size_t)(n0 + r) * 1024 + k0 + c] = f2h(tile[c][r]);
  }
}

// ---------------- fused QKV GEMM + l2norm + pack ----------------------------
__global__ __launch_bounds__(256, 3) void gemm_qkv_norm_kernel(
    const uint16_t* __restrict__ xc, const uint16_t* __restrict__ Wtc,
    const uint16_t* __restrict__ xr, const uint16_t* __restrict__ Wtr,
    uint16_t* __restrict__ Qc, uint16_t* __restrict__ Kc,
    uint16_t* __restrict__ Qr, uint16_t* __restrict__ Kr,
    uint16_t* __restrict__ Vt, uint16_t* __restrict__ Vcat,
    float* __restrict__ out) {
  __shared__ __align__(16) uint16_t pool[128 * 136];  // 34816 B
  __shared__ float rowss[2][128];
  uint16_t* As = pool;
  uint16_t* Bs = pool + 8192;

  int bm = blockIdx.x, bn = blockIdx.y;
  int n0 = bm * 128;
  const uint16_t* A;
  const uint16_t* Brow;
  int tz, h, iscls;
  if (bn < 24) {
    A = xc; Brow = Wtc + (size_t)(bn * 128) * 1024;
    tz = bn >> 3; h = bn & 7; iscls = 1;
  } else {
    int b2 = bn - 24;
    A = xr; Brow = Wtr + (size_t)(b2 * 128) * 1024;
    tz = b2 >> 3; h = b2 & 7; iscls = 0;
  }
  int tid = threadIdx.x;
  int w = tid >> 6, lane = tid & 63, quad = lane >> 4, l15 = lane & 15;
  int wm = (w >> 1) * 64, wn = (w & 1) * 64;
  const uint16_t* Arow = A + (size_t)n0 * 1024;
  f32x4 acc[4][4];
  f32x4 zero = {0.f, 0.f, 0.f, 0.f};
#pragma unroll
  for (int i = 0; i < 4; ++i)
#pragma unroll
    for (int j = 0; j < 4; ++j) acc[i][j] = zero;
  int rl = lane >> 3, cl = lane & 7;
  int sw = l15 & 7;
  for (int k0 = 0; k0 < 1024; k0 += 64) {
    __syncthreads();
#pragma unroll
    for (int t = 0; t < 4; ++t) {
      int r0 = w * 32 + t * 8;
      gld_lds16(Arow + (size_t)(r0 + rl) * 1024 + k0 + ((cl ^ rl) << 3), As + r0 * 64);
      gld_lds16(Brow + (size_t)(r0 + rl) * 1024 + k0 + ((cl ^ rl) << 3), Bs + r0 * 64);
    }
    __syncthreads();
#pragma unroll
    for (int ks = 0; ks < 2; ++ks) {
      f16x8 af[4], bf[4];
#pragma unroll
      for (int mt = 0; mt < 4; ++mt)
        af[mt] = ldfrag(As + (wm + mt * 16 + l15) * 64 + ((((ks << 2) + quad) ^ sw) << 3));
#pragma unroll
      for (int nt = 0; nt < 4; ++nt)
        bf[nt] = ldfrag(Bs + (wn + nt * 16 + l15) * 64 + ((((ks << 2) + quad) ^ sw) << 3));
#pragma unroll
      for (int mt = 0; mt < 4; ++mt)
#pragma unroll
        for (int nt = 0; nt < 4; ++nt)
          acc[mt][nt] = mfma16(af[mt], bf[nt], acc[mt][nt]);
    }
  }
  __syncthreads();  // (a)

  float ss[4][4];
#pragma unroll
  for (int mt = 0; mt < 4; ++mt)
#pragma unroll
    for (int r = 0; r < 4; ++r) {
      float s = 0.f;
#pragma unroll
      for (int nt = 0; nt < 4; ++nt) s += acc[mt][nt][r] * acc[mt][nt][r];
      s += __shfl_xor(s, 1);
      s += __shfl_xor(s, 2);
      s += __shfl_xor(s, 4);
      s += __shfl_xor(s, 8);
      ss[mt][r] = s;
    }
  int half = w & 1;
  if (l15 == 0) {
#pragma unroll
    for (int mt = 0; mt < 4; ++mt)
#pragma unroll
      for (int r = 0; r < 4; ++r)
        rowss[half][wm + mt * 16 + quad * 4 + r] = ss[mt][r];
  }
  __syncthreads();  // (b)
  float rn[4][4];
#pragma unroll
  for (int mt = 0; mt < 4; ++mt)
#pragma unroll
    for (int r = 0; r < 4; ++r) {
      int row = wm + mt * 16 + quad * 4 + r;
      rn[mt][r] = rsqrtf(rowss[0][row] + rowss[1][row]);
    }

  uint16_t* tile = pool;
#pragma unroll
  for (int mt = 0; mt < 4; ++mt)
#pragma unroll
    for (int nt = 0; nt < 4; ++nt)
#pragma unroll
      for (int r = 0; r < 4; ++r) {
        int row = wm + mt * 16 + quad * 4 + r;
        int col = wn + nt * 16 + l15;
        tile[row * 136 + col] = f2h(acc[mt][nt][r] * rn[mt][r]);
      }
  if (tz == 2) {
#pragma unroll
    for (int mt = 0; mt < 4; ++mt)
#pragma unroll
      for (int nt = 0; nt < 4; ++nt)
#pragma unroll
        for (int r = 0; r < 4; ++r) {
          int row = wm + mt * 16 + quad * 4 + r;
          int col = wn + nt * 16 + l15;
          out[(size_t)(n0 + row) * 2048 + 1024 + h * 128 + col] = acc[mt][nt][r];
        }
  }
  __syncthreads();  // (c)

  {
    int trow = tid >> 1, tco = (tid & 1) << 6;
    const uint16_t* src = tile + trow * 136 + tco;
    uint16_t* dst;
    size_t base;
    if (tz == 0) { dst = iscls ? Qc : Qr; base = ((size_t)h * 2048 + n0 + trow) * 128 + tco; }
    else if (tz == 1) { dst = iscls ? Kc : Kr; base = ((size_t)h * 2048 + n0 + trow) * 128 + tco; }
    else { dst = Vcat; base = (size_t)(n0 + trow) * 1024 + h * 128 + tco; }
#pragma unroll
    for (int j = 0; j < 8; ++j)
      *(i32x4*)(dst + base + j * 8) = *(const i32x4*)(src + j * 8);
  }

  if (tz == 2) {
    __syncthreads();  // (d)
#pragma unroll
    for (int mt = 0; mt < 4; ++mt)
#pragma unroll
      for (int nt = 0; nt < 4; ++nt)
#pragma unroll
        for (int r = 0; r < 4; ++r) {
          int row = wm + mt * 16 + quad * 4 + r;
          int col = wn + nt * 16 + l15;
          tile[col * 136 + row] = f2h(acc[mt][nt][r]);
        }
    __syncthreads();  // (e)
    int trow = tid >> 1, tco = (tid & 1) << 6;
    size_t base = ((size_t)h * 128 + trow) * 2048 + n0 + tco;
#pragma unroll
    for (int j = 0; j < 8; ++j)
      *(i32x4*)(Vt + base + j * 8) = *(const i32x4*)(tile + trow * 136 + tco + j * 8);
  }
}

// ---------------- mask GEMM: (Vcat.Vcat^T > 6) -> u8 ------------------------
__global__ __launch_bounds__(256, 3) void gemm_mask_kernel(
    const uint16_t* __restrict__ Vcat, uint8_t* __restrict__ mask) {
  __shared__ __align__(16) uint16_t As[128 * 64];
  __shared__ __align__(16) uint16_t Bs[128 * 64];
  int tid = threadIdx.x;
  int w = tid >> 6, lane = tid & 63, quad = lane >> 4, l15 = lane & 15;
  int wm = (w >> 1) * 64, wn = (w & 1) * 64;
  int bm = blockIdx.x, bn = blockIdx.y;
  const uint16_t* Arow = Vcat + (size_t)(bm * 128) * 1024;
  const uint16_t* Brow = Vcat + (size_t)(bn * 128) * 1024;
  f32x4 acc[4][4];
  f32x4 zero = {0.f, 0.f, 0.f, 0.f};
#pragma unroll
  for (int i = 0; i < 4; ++i)
#pragma unroll
    for (int j = 0; j < 4; ++j) acc[i][j] = zero;
  int rl = lane >> 3, cl = lane & 7;
  int sw = l15 & 7;
  for (int k0 = 0; k0 < 1024; k0 += 64) {
    __syncthreads();
#pragma unroll
    for (int t = 0; t < 4; ++t) {
      int r0 = w * 32 + t * 8;
      gld_lds16(Arow + (size_t)(r0 + rl) * 1024 + k0 + ((cl ^ rl) << 3), As + r0 * 64);
      gld_lds16(Brow + (size_t)(r0 + rl) * 1024 + k0 + ((cl ^ rl) << 3), Bs + r0 * 64);
    }
    __syncthreads();
#pragma unroll
    for (int ks = 0; ks < 2; ++ks) {
      f16x8 af[4], bf[4];
#pragma unroll
      for (int mt = 0; mt < 4; ++mt)
        af[mt] = ldfrag(As + (wm + mt * 16 + l15) * 64 + ((((ks << 2) + quad) ^ sw) << 3));
#pragma unroll
      for (int nt = 0; nt < 4; ++nt)
        bf[nt] = ldfrag(Bs + (wn + nt * 16 + l15) * 64 + ((((ks << 2) + quad) ^ sw) << 3));
#pragma unroll
      for (int mt = 0; mt < 4; ++mt)
#pragma unroll
        for (int nt = 0; nt < 4; ++nt)
          acc[mt][nt] = mfma16(af[mt], bf[nt], acc[mt][nt]);
    }
  }
#pragma unroll
  for (int mt = 0; mt < 4; ++mt)
#pragma unroll
    for (int nt = 0; nt < 4; ++nt) {
      int row = bm * 128 + wm + mt * 16 + quad * 4;
      int col = bn * 128 + wn + nt * 16 + l15;
#pragma unroll
      for (int r = 0; r < 4; ++r)
        mask[(size_t)(row + r) * 2048 + col] = (acc[mt][nt][r] > 6.0f) ? 1 : 0;
    }
}

// ---------------- flash attention: R5 geometry + transposed-S ---------------
// grid 1024: h=bx&7; rest=bx>>3: s=rest&1 (m-split), p=(rest>>1)&1, q64=rest>>2.
// Wave w: 16 q-rows. Bk=64, 16 iters. LDS 40960B -> 3 blocks/CU.
// QK computed as S^T = K·Q^T (K=A-operand): softmax per-lane (q=l15), in-lane
// reduction over 16 m + 2 cross-quad shuffles. M/L are per-lane scalars.
__global__ __launch_bounds__(256, 4) void attn_kernel(
    const uint16_t* __restrict__ Qc, const uint16_t* __restrict__ Kc,
    const uint16_t* __restrict__ Qr, const uint16_t* __restrict__ Kr,
    const uint16_t* __restrict__ Vt,
    const float* __restrict__ cls_score, const float* __restrict__ fg_score,
    uint16_t* __restrict__ Opart, float* __restrict__ Mpart,
    float* __restrict__ Lpart) {
  __shared__ __align__(16) uint16_t sK[64 * 128];    // 16 KB
  __shared__ __align__(16) uint16_t sVt[128 * 64];   // 16 KB
  __shared__ __align__(16) uint16_t sP[4 * 16 * 64]; // 8 KB

  int bx = blockIdx.x;
  int h = bx & 7;
  int rest = bx >> 3;
  int s_ = rest & 1;
  int p = (rest >> 1) & 1;
  int q64 = rest >> 2;
  int tid = threadIdx.x, w = tid >> 6, lane = tid & 63;
  int quad = lane >> 4, l15 = lane & 15;
  int qbase = q64 * 64 + w * 16;
  int mstart = s_ * 1024;
  uint16_t* Pb = sP + w * 1024;

  const uint16_t* Qp = p ? Qr : Qc;
  const float* score = p ? fg_score : cls_score;
  const uint16_t* Kh = (p ? Kr : Kc) + (size_t)h * 2048 * 128;
  const uint16_t* Vh = Vt + (size_t)h * 128 * 2048;

  f16x8 qf[4];
  const uint16_t* qp = Qp + ((size_t)h * 2048 + qbase + l15) * 128;
#pragma unroll
  for (int ks = 0; ks < 4; ++ks) qf[ks] = ldfrag(qp + ks * 32 + quad * 8);

  float sqv = score[qbase + l15] - 0.1f;  // per-lane q threshold

  float M = -3.0e38f, Lacc = 0.f;
  f32x4 O[8];
  f32x4 zero = {0.f, 0.f, 0.f, 0.f};
#pragma unroll
  for (int i = 0; i < 8; ++i) O[i] = zero;

  int krl = lane >> 4, kcl = lane & 15;
  int vrl = lane >> 3, vcl = lane & 7;
  int xk = l15 & 7;

  for (int it = 0; it < 16; ++it) {
    int m0 = mstart + it * 64;
    __syncthreads();
#pragma unroll
    for (int t = 0; t < 4; ++t) {
      int r0 = w * 16 + t * 4;
      int key = (r0 + krl) & 7;
      gld_lds16(Kh + (size_t)(m0 + r0 + krl) * 128 + ((kcl ^ key) << 3),
                sK + r0 * 128);
    }
#pragma unroll
    for (int t = 0; t < 4; ++t) {
      int d0 = w * 32 + t * 8;
      gld_lds16(Vh + (size_t)(d0 + vrl) * 2048 + m0 + ((vcl ^ vrl) << 3),
                sVt + d0 * 64);
    }
    __syncthreads();

    // S^T = K·Q^T: per lane holds S^T[m=mt*16+quad*4+r][q=l15]
    f32x4 S[4];
#pragma unroll
    for (int mt = 0; mt < 4; ++mt) S[mt] = zero;
#pragma unroll
    for (int ks = 0; ks < 4; ++ks)
#pragma unroll
      for (int mt = 0; mt < 4; ++mt) {
        f16x8 kf = ldfrag(sK + (mt * 16 + l15) * 128 + (((ks * 4 + quad) ^ xk) << 3));
        S[mt] = mfma16(kf, qf[ks], S[mt]);
      }

    // scale + mask (scores for this lane's 16 m values)
    float4 scm4[4];
#pragma unroll
    for (int mt = 0; mt < 4; ++mt)
      scm4[mt] = *(const float4*)(score + m0 + mt * 16 + quad * 4);
    float l2v[4][4];
    float vmax = -3.0e38f;
#pragma unroll
    for (int mt = 0; mt < 4; ++mt) {
      float sc0 = ((const float*)&scm4[mt])[0];
      float sc1 = ((const float*)&scm4[mt])[1];
      float sc2 = ((const float*)&scm4[mt])[2];
      float sc3 = ((const float*)&scm4[mt])[3];
      l2v[mt][0] = (sc0 > sqv) ? S[mt][0] * (sc0 * SC25) : 0.0f;
      l2v[mt][1] = (sc1 > sqv) ? S[mt][1] * (sc1 * SC25) : 0.0f;
      l2v[mt][2] = (sc2 > sqv) ? S[mt][2] * (sc2 * SC25) : 0.0f;
      l2v[mt][3] = (sc3 > sqv) ? S[mt][3] * (sc3 * SC25) : 0.0f;
#pragma unroll
      for (int r = 0; r < 4; ++r) vmax = fmaxf(vmax, l2v[mt][r]);
    }
    // cross-quad max (quads hold disjoint m)
    vmax = fmaxf(vmax, __shfl_xor(vmax, 16));
    vmax = fmaxf(vmax, __shfl_xor(vmax, 32));
    float Mnew = fmaxf(M, vmax);
    float al = __builtin_amdgcn_exp2f(M - Mnew);
    M = Mnew;

    float ssum = 0.f;
#pragma unroll
    for (int mt = 0; mt < 4; ++mt)
#pragma unroll
      for (int r = 0; r < 4; ++r) {
        float pe = __builtin_amdgcn_exp2f(l2v[mt][r] - Mnew);
        l2v[mt][r] = pe;
        ssum += pe;
      }
    Lacc = Lacc * al + ssum;

    // O rescale (skip when no lane changed its max)
    unsigned long long anyresc = __ballot(al != 1.0f);
    if (anyresc) {
      float alr[4];
#pragma unroll
      for (int r = 0; r < 4; ++r) alr[r] = __shfl(al, quad * 4 + r);
#pragma unroll
      for (int dt = 0; dt < 8; ++dt)
#pragma unroll
        for (int r = 0; r < 4; ++r) O[dt][r] *= alr[r];
    }

    // P^T -> Pb rows=q(l15), cols=m, XOR-swizzled segments
#pragma unroll
    for (int mt = 0; mt < 4; ++mt)
#pragma unroll
      for (int r = 0; r < 4; ++r) {
        int mloc = mt * 16 + quad * 4 + r;
        Pb[l15 * 64 + (((mloc >> 3) ^ xk) << 3) + (mloc & 7)] = f2h(l2v[mt][r]);
      }
    // PV
#pragma unroll
    for (int ks2 = 0; ks2 < 2; ++ks2) {
      f16x8 a = ldfrag(Pb + l15 * 64 + (((ks2 * 4 + quad) ^ xk) << 3));
#pragma unroll
      for (int dt = 0; dt < 8; ++dt) {
        f16x8 b = ldfrag(sVt + (dt * 16 + l15) * 64 + (((ks2 * 4 + quad) ^ xk) << 3));
        O[dt] = mfma16(a, b, O[dt]);
      }
    }
  }

  // final: L covers this lane's quad-subset -> cross-quad sum
  Lacc += __shfl_xor(Lacc, 16);
  Lacc += __shfl_xor(Lacc, 32);

  int plane = p * 2 + s_;
  uint16_t* Op = Opart + (size_t)plane * 2097152;
#pragma unroll
  for (int dt = 0; dt < 8; ++dt)
#pragma unroll
    for (int r = 0; r < 4; ++r)
      Op[(size_t)(qbase + quad * 4 + r) * 1024 + h * 128 + dt * 16 + l15] =
          f2h(O[dt][r]);
  if (lane < 16) {
    int qrow = qbase + lane;
    Mpart[((size_t)plane * 8 + h) * 2048 + qrow] = M;
    Lpart[((size_t)plane * 8 + h) * 2048 + qrow] = Lacc;
  }
}

// ---------------- fused combine + sim_round2 --------------------------------
__global__ __launch_bounds__(256) void combine_sim_kernel(
    const uint16_t* __restrict__ Opart, const float* __restrict__ Mpart,
    const float* __restrict__ Lpart, const uint8_t* __restrict__ mask,
    const uint16_t* __restrict__ Qc, const uint16_t* __restrict__ Kc,
    const uint16_t* __restrict__ Qr, const uint16_t* __restrict__ Kr,
    const float* __restrict__ cls_score, const float* __restrict__ fg_score,
    float* __restrict__ out, float* __restrict__ simout) {
  int n = blockIdx.x;
  int t = threadIdx.x;
  __shared__ float sM[2][8], sL[2][8];
  __shared__ float red[4];
  __shared__ float s_inv;
  if (t < 16) {
    int p = t >> 3, hh = t & 7;
    size_t i1 = ((size_t)(p * 2 + 0) * 8 + hh) * 2048 + n;
    size_t i2 = ((size_t)(p * 2 + 1) * 8 + hh) * 2048 + n;
    float M1 = Mpart[i1], M2 = Mpart[i2];
    float L1 = Lpart[i1], L2 = Lpart[i2];
    float Mx = fmaxf(M1, M2);
    float Lx = L1 * __builtin_amdgcn_exp2f(M1 - Mx) +
               L2 * __builtin_amdgcn_exp2f(M2 - Mx);
    sM[p][hh] = Mx;
    sL[p][hh] = Lx;
  }
  __syncthreads();

  {
    int col = t * 4;
    int h = col >> 7;
    float res[4] = {0.f, 0.f, 0.f, 0.f};
#pragma unroll
    for (int p = 0; p < 2; ++p) {
      size_t i1 = ((size_t)(p * 2 + 0) * 8 + h) * 2048 + n;
      size_t i2 = ((size_t)(p * 2 + 1) * 8 + h) * 2048 + n;
      float Mx = sM[p][h];
      float iLx = 0.5f / sL[p][h];
      float f1 = __builtin_amdgcn_exp2f(Mpart[i1] - Mx) * iLx;
      float f2 = __builtin_amdgcn_exp2f(Mpart[i2] - Mx) * iLx;
      const uint16_t* O1 = Opart + (size_t)(p * 2 + 0) * 2097152 + (size_t)n * 1024 + col;
      const uint16_t* O2 = Opart + (size_t)(p * 2 + 1) * 2097152 + (size_t)n * 1024 + col;
      ushort4 a1 = *(const ushort4*)O1;
      ushort4 a2 = *(const ushort4*)O2;
      res[0] += h2f(a1.x) * f1 + h2f(a2.x) * f2;
      res[1] += h2f(a1.y) * f1 + h2f(a2.y) * f2;
      res[2] += h2f(a1.z) * f1 + h2f(a2.z) * f2;
      res[3] += h2f(a1.w) * f1 + h2f(a2.w) * f2;
    }
    float4 r4 = {res[0], res[1], res[2], res[3]};
    *(float4*)(out + (size_t)n * 2048 + col) = r4;
  }

  // sim_round2: thread t owns m = t*8..t*8+7; vectorized f16x8 dot products
  int mbase = t * 8;
  union { unsigned long long v; uint8_t b[8]; } mk;
  mk.v = *(const unsigned long long*)(mask + (size_t)n * 2048 + mbase);
  float e[8];
  float psum = 0.f;
  float cs_n = cls_score[n] - 0.1f, fs_n = fg_score[n] - 0.1f;
#pragma unroll
  for (int i = 0; i < 8; ++i) {
    int m = mbase + i;
    float val = 0.f;
    if (mk.b[i]) {
      float s = 0.f;
      float c2 = SC25 * cls_score[m];
      float r2 = SC25 * fg_score[m];
      float mc = (cls_score[m] > cs_n) ? 1.f : 0.f;
      float mr = (fg_score[m] > fs_n) ? 1.f : 0.f;
      for (int hh = 0; hh < 8; ++hh) {
        const uint16_t* qc = Qc + ((size_t)hh * 2048 + n) * 128;
        const uint16_t* kc = Kc + ((size_t)hh * 2048 + m) * 128;
        const uint16_t* qr = Qr + ((size_t)hh * 2048 + n) * 128;
        const uint16_t* kr = Kr + ((size_t)hh * 2048 + m) * 128;
        float d0 = 0.f, d1 = 0.f, e0 = 0.f, e1 = 0.f;
#pragma unroll
        for (int c = 0; c < 16; ++c) {
          f16x8 qv = ldfrag(qc + c * 8);
          f16x8 kv = ldfrag(kc + c * 8);
          f16x8 q2 = ldfrag(qr + c * 8);
          f16x8 k2 = ldfrag(kr + c * 8);
#pragma unroll
          for (int j = 0; j < 8; j += 2) {
            d0 += (float)qv[j] * (float)kv[j];
            d1 += (float)qv[j + 1] * (float)kv[j + 1];
            e0 += (float)q2[j] * (float)k2[j];
            e1 += (float)q2[j + 1] * (float)k2[j + 1];
          }
        }
        float lc = (d0 + d1) * c2 * mc;
        float lr = (e0 + e1) * r2 * mr;
        float ac = __builtin_amdgcn_exp2f(lc - sM[0][hh]) / sL[0][hh];
        float ar = __builtin_amdgcn_exp2f(lr - sM[1][hh]) / sL[1][hh];
        s += ac + ar;
      }
      s *= (1.0f / 16.0f);
      val = __builtin_amdgcn_exp2f(s * K2E);
    }
    e[i] = val;
    psum += val;
  }
  for (int off = 1; off < 64; off <<= 1) psum += __shfl_xor(psum, off);
  if ((t & 63) == 0) red[t >> 6] = psum;
  __syncthreads();
  if (t == 0) s_inv = 1.0f / (red[0] + red[1] + red[2] + red[3]);
  __syncthreads();
  float inv = s_inv;
  float4 r0 = {e[0] * inv, e[1] * inv, e[2] * inv, e[3] * inv};
  float4 r1 = {e[4] * inv, e[5] * inv, e[6] * inv, e[7] * inv};
  *(float4*)(simout + (size_t)n * 2048 + mbase) = r0;
  *(float4*)(simout + (size_t)n * 2048 + mbase + 4) = r1;
}

// ---------------- host launch ------------------------------------------------
extern "C" void kernel_launch(void* const* d_in, const int* in_sizes, int n_in,
                              void* d_out, int out_size, void* d_ws, size_t ws_size,
                              hipStream_t stream) {
  const float* x_cls = (const float*)d_in[0];
  const float* x_reg = (const float*)d_in[1];
  const float* cls_score = (const float*)d_in[2];
  const float* fg_score = (const float*)d_in[3];
  const float* W_cls = (const float*)d_in[4];
  const float* W_reg = (const float*)d_in[5];
  float* out = (float*)d_out;
  char* ws = (char*)d_ws;

  const size_t OFF_XC   = 0;
  const size_t OFF_XR   = OFF_XC + 4194304;
  const size_t OFF_WTC  = OFF_XR + 4194304;
  const size_t OFF_WTR  = OFF_WTC + 6291456;
  const size_t OFF_QC   = OFF_WTR + 4194304;
  const size_t OFF_KC   = OFF_QC + 4194304;
  const size_t OFF_QR   = OFF_KC + 4194304;
  const size_t OFF_KR   = OFF_QR + 4194304;
  const size_t OFF_VT   = OFF_KR + 4194304;
  const size_t OFF_VCAT = OFF_VT + 4194304;
  const size_t OFF_OP   = OFF_VCAT + 4194304;   // 16 MB
  const size_t OFF_MP   = OFF_OP + 16777216;    // 256 KB
  const size_t OFF_LP   = OFF_MP + 262144;      // 256 KB
  const size_t OFF_MASK = OFF_LP + 262144;      // 4 MB

  uint16_t* xc_b = (uint16_t*)(ws + OFF_XC);
  uint16_t* xr_b = (uint16_t*)(ws + OFF_XR);
  uint16_t* Wtc  = (uint16_t*)(ws + OFF_WTC);
  uint16_t* Wtr  = (uint16_t*)(ws + OFF_WTR);
  uint16_t* Qc   = (uint16_t*)(ws + OFF_QC);
  uint16_t* Kc   = (uint16_t*)(ws + OFF_KC);
  uint16_t* Qr   = (uint16_t*)(ws + OFF_QR);
  uint16_t* Kr   = (uint16_t*)(ws + OFF_KR);
  uint16_t* Vt   = (uint16_t*)(ws + OFF_VT);
  uint16_t* Vcat = (uint16_t*)(ws + OFF_VCAT);
  uint16_t* Opart = (uint16_t*)(ws + OFF_OP);
  float* Mpart   = (float*)(ws + OFF_MP);
  float* Lpart   = (float*)(ws + OFF_LP);
  uint8_t* mask  = (uint8_t*)(ws + OFF_MASK);

  prep_kernel<<<3328, 256, 0, stream>>>(x_cls, x_reg, W_cls, W_reg,
                                        xc_b, xr_b, Wtc, Wtr);
  gemm_qkv_norm_kernel<<<dim3(16, 40), 256, 0, stream>>>(
      xc_b, Wtc, xr_b, Wtr, Qc, Kc, Qr, Kr, Vt, Vcat, out);
  gemm_mask_kernel<<<dim3(16, 16), 256, 0, stream>>>(Vcat, mask);
  attn_kernel<<<1024, 256, 0, stream>>>(Qc, Kc, Qr, Kr, Vt, cls_score, fg_score,
                                        Opart, Mpart, Lpart);
  combine_sim_kernel<<<2048, 256, 0, stream>>>(Opart, Mpart, Lpart, mask,
                                               Qc, Kc, Qr, Kr, cls_score,
                                               fg_score, out, out + 4194304);
}

// Round 8
// 225.864 us; speedup vs baseline: 1.6435x; 1.3025x over previous
//
#include <hip/hip_runtime.h>
#include <stdint.h>
#include <stddef.h>

#define DEV __device__ __forceinline__

typedef _Float16 f16x8 __attribute__((ext_vector_type(8)));
typedef float    f32x4 __attribute__((ext_vector_type(4)));
typedef int      i32x4 __attribute__((ext_vector_type(4)));

#define K2E 1.44269504088896340736f
#define SC25 (25.0f * K2E)

DEV uint16_t f2h(float f) {
  _Float16 h = (_Float16)f;
  return __builtin_bit_cast(uint16_t, h);
}
DEV float h2f(uint16_t u) {
  return (float)__builtin_bit_cast(_Float16, u);
}
DEV f16x8 ldfrag(const uint16_t* p) {
  i32x4 v = *(const i32x4*)p;
  return __builtin_bit_cast(f16x8, v);
}
DEV f32x4 mfma16(f16x8 a, f16x8 b, f32x4 c) {
  return __builtin_amdgcn_mfma_f32_16x16x32_f16(a, b, c, 0, 0, 0);
}
// async global->LDS: each lane copies 16B; LDS dest = base + lane*16
DEV void gld_lds16(const uint16_t* g, uint16_t* l) {
  __builtin_amdgcn_global_load_lds(
      (__attribute__((address_space(1))) void*)g,
      (__attribute__((address_space(3))) void*)l, 16, 0, 0);
}

union U16x8 { uint16_t u[8]; i32x4 v; };

// ---------------- fused prep: casts + weight transposes ---------------------
__global__ __launch_bounds__(256) void prep_kernel(
    const float* __restrict__ x_cls, const float* __restrict__ x_reg,
    const float* __restrict__ W_cls, const float* __restrict__ W_reg,
    uint16_t* __restrict__ xc_b, uint16_t* __restrict__ xr_b,
    uint16_t* __restrict__ Wtc, uint16_t* __restrict__ Wtr) {
  __shared__ float tile[64][65];
  int b = blockIdx.x, tid = threadIdx.x;
  if (b < 2048) {
    const float* in = (b < 1024) ? x_cls : x_reg;
    uint16_t* outp = (b < 1024) ? xc_b : xr_b;
    int i = (b & 1023) * 256 + tid;
    float4 a = *(const float4*)(in + (size_t)i * 8);
    float4 c = *(const float4*)(in + (size_t)i * 8 + 4);
    U16x8 r;
    r.u[0] = f2h(a.x); r.u[1] = f2h(a.y); r.u[2] = f2h(a.z); r.u[3] = f2h(a.w);
    r.u[4] = f2h(c.x); r.u[5] = f2h(c.y); r.u[6] = f2h(c.z); r.u[7] = f2h(c.w);
    *(i32x4*)(outp + (size_t)i * 8) = r.v;
    return;
  }
  const float* W;
  uint16_t* Wt;
  int idx;
  if (b < 2816) { W = W_cls; Wt = Wtc; idx = b - 2048; }
  else          { W = W_reg; Wt = Wtr; idx = b - 2816; }
  int k0 = (idx & 15) * 64;
  int n0 = (idx >> 4) * 64;
#pragma unroll
  for (int i = 0; i < 16; ++i) {
    int flat = i * 256 + tid;
    int r = flat >> 6, c = flat & 63;
    tile[r][c] = W[(size_t)(k0 + r) * 3072 + n0 + c];
  }
  __syncthreads();
#pragma unroll
  for (int i = 0; i < 16; ++i) {
    int flat = i * 256 + tid;
    int r = flat >> 6, c = flat & 63;
    Wt[(size_t)(n0 + r) * 1024 + k0 + c] = f2h(tile[c][r]);
  }
}

// ---------------- fused QKV GEMM + l2norm + pack ----------------------------
__global__ __launch_bounds__(256, 3) void gemm_qkv_norm_kernel(
    const uint16_t* __restrict__ xc, const uint16_t* __restrict__ Wtc,
    const uint16_t* __restrict__ xr, const uint16_t* __restrict__ Wtr,
    uint16_t* __restrict__ Qc, uint16_t* __restrict__ Kc,
    uint16_t* __restrict__ Qr, uint16_t* __restrict__ Kr,
    uint16_t* __restrict__ Vt, uint16_t* __restrict__ Vcat,
    float* __restrict__ out) {
  __shared__ __align__(16) uint16_t pool[128 * 136];  // 34816 B
  __shared__ float rowss[2][128];
  uint16_t* As = pool;
  uint16_t* Bs = pool + 8192;

  int bm = blockIdx.x, bn = blockIdx.y;
  int n0 = bm * 128;
  const uint16_t* A;
  const uint16_t* Brow;
  int tz, h, iscls;
  if (bn < 24) {
    A = xc; Brow = Wtc + (size_t)(bn * 128) * 1024;
    tz = bn >> 3; h = bn & 7; iscls = 1;
  } else {
    int b2 = bn - 24;
    A = xr; Brow = Wtr + (size_t)(b2 * 128) * 1024;
    tz = b2 >> 3; h = b2 & 7; iscls = 0;
  }
  int tid = threadIdx.x;
  int w = tid >> 6, lane = tid & 63, quad = lane >> 4, l15 = lane & 15;
  int wm = (w >> 1) * 64, wn = (w & 1) * 64;
  const uint16_t* Arow = A + (size_t)n0 * 1024;
  f32x4 acc[4][4];
  f32x4 zero = {0.f, 0.f, 0.f, 0.f};
#pragma unroll
  for (int i = 0; i < 4; ++i)
#pragma unroll
    for (int j = 0; j < 4; ++j) acc[i][j] = zero;
  int rl = lane >> 3, cl = lane & 7;
  int sw = l15 & 7;
  for (int k0 = 0; k0 < 1024; k0 += 64) {
    __syncthreads();
#pragma unroll
    for (int t = 0; t < 4; ++t) {
      int r0 = w * 32 + t * 8;
      gld_lds16(Arow + (size_t)(r0 + rl) * 1024 + k0 + ((cl ^ rl) << 3), As + r0 * 64);
      gld_lds16(Brow + (size_t)(r0 + rl) * 1024 + k0 + ((cl ^ rl) << 3), Bs + r0 * 64);
    }
    __syncthreads();
#pragma unroll
    for (int ks = 0; ks < 2; ++ks) {
      f16x8 af[4], bf[4];
#pragma unroll
      for (int mt = 0; mt < 4; ++mt)
        af[mt] = ldfrag(As + (wm + mt * 16 + l15) * 64 + ((((ks << 2) + quad) ^ sw) << 3));
#pragma unroll
      for (int nt = 0; nt < 4; ++nt)
        bf[nt] = ldfrag(Bs + (wn + nt * 16 + l15) * 64 + ((((ks << 2) + quad) ^ sw) << 3));
#pragma unroll
      for (int mt = 0; mt < 4; ++mt)
#pragma unroll
        for (int nt = 0; nt < 4; ++nt)
          acc[mt][nt] = mfma16(af[mt], bf[nt], acc[mt][nt]);
    }
  }
  __syncthreads();  // (a)

  float ss[4][4];
#pragma unroll
  for (int mt = 0; mt < 4; ++mt)
#pragma unroll
    for (int r = 0; r < 4; ++r) {
      float s = 0.f;
#pragma unroll
      for (int nt = 0; nt < 4; ++nt) s += acc[mt][nt][r] * acc[mt][nt][r];
      s += __shfl_xor(s, 1);
      s += __shfl_xor(s, 2);
      s += __shfl_xor(s, 4);
      s += __shfl_xor(s, 8);
      ss[mt][r] = s;
    }
  int half = w & 1;
  if (l15 == 0) {
#pragma unroll
    for (int mt = 0; mt < 4; ++mt)
#pragma unroll
      for (int r = 0; r < 4; ++r)
        rowss[half][wm + mt * 16 + quad * 4 + r] = ss[mt][r];
  }
  __syncthreads();  // (b)
  float rn[4][4];
#pragma unroll
  for (int mt = 0; mt < 4; ++mt)
#pragma unroll
    for (int r = 0; r < 4; ++r) {
      int row = wm + mt * 16 + quad * 4 + r;
      rn[mt][r] = rsqrtf(rowss[0][row] + rowss[1][row]);
    }

  uint16_t* tile = pool;
#pragma unroll
  for (int mt = 0; mt < 4; ++mt)
#pragma unroll
    for (int nt = 0; nt < 4; ++nt)
#pragma unroll
      for (int r = 0; r < 4; ++r) {
        int row = wm + mt * 16 + quad * 4 + r;
        int col = wn + nt * 16 + l15;
        tile[row * 136 + col] = f2h(acc[mt][nt][r] * rn[mt][r]);
      }
  if (tz == 2) {
#pragma unroll
    for (int mt = 0; mt < 4; ++mt)
#pragma unroll
      for (int nt = 0; nt < 4; ++nt)
#pragma unroll
        for (int r = 0; r < 4; ++r) {
          int row = wm + mt * 16 + quad * 4 + r;
          int col = wn + nt * 16 + l15;
          out[(size_t)(n0 + row) * 2048 + 1024 + h * 128 + col] = acc[mt][nt][r];
        }
  }
  __syncthreads();  // (c)

  {
    int trow = tid >> 1, tco = (tid & 1) << 6;
    const uint16_t* src = tile + trow * 136 + tco;
    uint16_t* dst;
    size_t base;
    if (tz == 0) { dst = iscls ? Qc : Qr; base = ((size_t)h * 2048 + n0 + trow) * 128 + tco; }
    else if (tz == 1) { dst = iscls ? Kc : Kr; base = ((size_t)h * 2048 + n0 + trow) * 128 + tco; }
    else { dst = Vcat; base = (size_t)(n0 + trow) * 1024 + h * 128 + tco; }
#pragma unroll
    for (int j = 0; j < 8; ++j)
      *(i32x4*)(dst + base + j * 8) = *(const i32x4*)(src + j * 8);
  }

  if (tz == 2) {
    __syncthreads();  // (d)
#pragma unroll
    for (int mt = 0; mt < 4; ++mt)
#pragma unroll
      for (int nt = 0; nt < 4; ++nt)
#pragma unroll
        for (int r = 0; r < 4; ++r) {
          int row = wm + mt * 16 + quad * 4 + r;
          int col = wn + nt * 16 + l15;
          tile[col * 136 + row] = f2h(acc[mt][nt][r]);
        }
    __syncthreads();  // (e)
    int trow = tid >> 1, tco = (tid & 1) << 6;
    size_t base = ((size_t)h * 128 + trow) * 2048 + n0 + tco;
#pragma unroll
    for (int j = 0; j < 8; ++j)
      *(i32x4*)(Vt + base + j * 8) = *(const i32x4*)(tile + trow * 136 + tco + j * 8);
  }
}

// ---------------- mask GEMM: (Vcat.Vcat^T > 6) -> u8 ------------------------
__global__ __launch_bounds__(256, 3) void gemm_mask_kernel(
    const uint16_t* __restrict__ Vcat, uint8_t* __restrict__ mask) {
  __shared__ __align__(16) uint16_t As[128 * 64];
  __shared__ __align__(16) uint16_t Bs[128 * 64];
  int tid = threadIdx.x;
  int w = tid >> 6, lane = tid & 63, quad = lane >> 4, l15 = lane & 15;
  int wm = (w >> 1) * 64, wn = (w & 1) * 64;
  int bm = blockIdx.x, bn = blockIdx.y;
  const uint16_t* Arow = Vcat + (size_t)(bm * 128) * 1024;
  const uint16_t* Brow = Vcat + (size_t)(bn * 128) * 1024;
  f32x4 acc[4][4];
  f32x4 zero = {0.f, 0.f, 0.f, 0.f};
#pragma unroll
  for (int i = 0; i < 4; ++i)
#pragma unroll
    for (int j = 0; j < 4; ++j) acc[i][j] = zero;
  int rl = lane >> 3, cl = lane & 7;
  int sw = l15 & 7;
  for (int k0 = 0; k0 < 1024; k0 += 64) {
    __syncthreads();
#pragma unroll
    for (int t = 0; t < 4; ++t) {
      int r0 = w * 32 + t * 8;
      gld_lds16(Arow + (size_t)(r0 + rl) * 1024 + k0 + ((cl ^ rl) << 3), As + r0 * 64);
      gld_lds16(Brow + (size_t)(r0 + rl) * 1024 + k0 + ((cl ^ rl) << 3), Bs + r0 * 64);
    }
    __syncthreads();
#pragma unroll
    for (int ks = 0; ks < 2; ++ks) {
      f16x8 af[4], bf[4];
#pragma unroll
      for (int mt = 0; mt < 4; ++mt)
        af[mt] = ldfrag(As + (wm + mt * 16 + l15) * 64 + ((((ks << 2) + quad) ^ sw) << 3));
#pragma unroll
      for (int nt = 0; nt < 4; ++nt)
        bf[nt] = ldfrag(Bs + (wn + nt * 16 + l15) * 64 + ((((ks << 2) + quad) ^ sw) << 3));
#pragma unroll
      for (int mt = 0; mt < 4; ++mt)
#pragma unroll
        for (int nt = 0; nt < 4; ++nt)
          acc[mt][nt] = mfma16(af[mt], bf[nt], acc[mt][nt]);
    }
  }
#pragma unroll
  for (int mt = 0; mt < 4; ++mt)
#pragma unroll
    for (int nt = 0; nt < 4; ++nt) {
      int row = bm * 128 + wm + mt * 16 + quad * 4;
      int col = bn * 128 + wn + nt * 16 + l15;
#pragma unroll
      for (int r = 0; r < 4; ++r)
        mask[(size_t)(row + r) * 2048 + col] = (acc[mt][nt][r] > 6.0f) ? 1 : 0;
    }
}

// ---------------- flash attention: transposed-S (unchanged from R7) ---------
__global__ __launch_bounds__(256, 4) void attn_kernel(
    const uint16_t* __restrict__ Qc, const uint16_t* __restrict__ Kc,
    const uint16_t* __restrict__ Qr, const uint16_t* __restrict__ Kr,
    const uint16_t* __restrict__ Vt,
    const float* __restrict__ cls_score, const float* __restrict__ fg_score,
    uint16_t* __restrict__ Opart, float* __restrict__ Mpart,
    float* __restrict__ Lpart) {
  __shared__ __align__(16) uint16_t sK[64 * 128];    // 16 KB
  __shared__ __align__(16) uint16_t sVt[128 * 64];   // 16 KB
  __shared__ __align__(16) uint16_t sP[4 * 16 * 64]; // 8 KB

  int bx = blockIdx.x;
  int h = bx & 7;
  int rest = bx >> 3;
  int s_ = rest & 1;
  int p = (rest >> 1) & 1;
  int q64 = rest >> 2;
  int tid = threadIdx.x, w = tid >> 6, lane = tid & 63;
  int quad = lane >> 4, l15 = lane & 15;
  int qbase = q64 * 64 + w * 16;
  int mstart = s_ * 1024;
  uint16_t* Pb = sP + w * 1024;

  const uint16_t* Qp = p ? Qr : Qc;
  const float* score = p ? fg_score : cls_score;
  const uint16_t* Kh = (p ? Kr : Kc) + (size_t)h * 2048 * 128;
  const uint16_t* Vh = Vt + (size_t)h * 128 * 2048;

  f16x8 qf[4];
  const uint16_t* qp = Qp + ((size_t)h * 2048 + qbase + l15) * 128;
#pragma unroll
  for (int ks = 0; ks < 4; ++ks) qf[ks] = ldfrag(qp + ks * 32 + quad * 8);

  float sqv = score[qbase + l15] - 0.1f;

  float M = -3.0e38f, Lacc = 0.f;
  f32x4 O[8];
  f32x4 zero = {0.f, 0.f, 0.f, 0.f};
#pragma unroll
  for (int i = 0; i < 8; ++i) O[i] = zero;

  int krl = lane >> 4, kcl = lane & 15;
  int vrl = lane >> 3, vcl = lane & 7;
  int xk = l15 & 7;

  for (int it = 0; it < 16; ++it) {
    int m0 = mstart + it * 64;
    __syncthreads();
#pragma unroll
    for (int t = 0; t < 4; ++t) {
      int r0 = w * 16 + t * 4;
      int key = (r0 + krl) & 7;
      gld_lds16(Kh + (size_t)(m0 + r0 + krl) * 128 + ((kcl ^ key) << 3),
                sK + r0 * 128);
    }
#pragma unroll
    for (int t = 0; t < 4; ++t) {
      int d0 = w * 32 + t * 8;
      gld_lds16(Vh + (size_t)(d0 + vrl) * 2048 + m0 + ((vcl ^ vrl) << 3),
                sVt + d0 * 64);
    }
    __syncthreads();

    f32x4 S[4];
#pragma unroll
    for (int mt = 0; mt < 4; ++mt) S[mt] = zero;
#pragma unroll
    for (int ks = 0; ks < 4; ++ks)
#pragma unroll
      for (int mt = 0; mt < 4; ++mt) {
        f16x8 kf = ldfrag(sK + (mt * 16 + l15) * 128 + (((ks * 4 + quad) ^ xk) << 3));
        S[mt] = mfma16(kf, qf[ks], S[mt]);
      }

    float4 scm4[4];
#pragma unroll
    for (int mt = 0; mt < 4; ++mt)
      scm4[mt] = *(const float4*)(score + m0 + mt * 16 + quad * 4);
    float l2v[4][4];
    float vmax = -3.0e38f;
#pragma unroll
    for (int mt = 0; mt < 4; ++mt) {
      float sc0 = ((const float*)&scm4[mt])[0];
      float sc1 = ((const float*)&scm4[mt])[1];
      float sc2 = ((const float*)&scm4[mt])[2];
      float sc3 = ((const float*)&scm4[mt])[3];
      l2v[mt][0] = (sc0 > sqv) ? S[mt][0] * (sc0 * SC25) : 0.0f;
      l2v[mt][1] = (sc1 > sqv) ? S[mt][1] * (sc1 * SC25) : 0.0f;
      l2v[mt][2] = (sc2 > sqv) ? S[mt][2] * (sc2 * SC25) : 0.0f;
      l2v[mt][3] = (sc3 > sqv) ? S[mt][3] * (sc3 * SC25) : 0.0f;
#pragma unroll
      for (int r = 0; r < 4; ++r) vmax = fmaxf(vmax, l2v[mt][r]);
    }
    vmax = fmaxf(vmax, __shfl_xor(vmax, 16));
    vmax = fmaxf(vmax, __shfl_xor(vmax, 32));
    float Mnew = fmaxf(M, vmax);
    float al = __builtin_amdgcn_exp2f(M - Mnew);
    M = Mnew;

    float ssum = 0.f;
#pragma unroll
    for (int mt = 0; mt < 4; ++mt)
#pragma unroll
      for (int r = 0; r < 4; ++r) {
        float pe = __builtin_amdgcn_exp2f(l2v[mt][r] - Mnew);
        l2v[mt][r] = pe;
        ssum += pe;
      }
    Lacc = Lacc * al + ssum;

    unsigned long long anyresc = __ballot(al != 1.0f);
    if (anyresc) {
      float alr[4];
#pragma unroll
      for (int r = 0; r < 4; ++r) alr[r] = __shfl(al, quad * 4 + r);
#pragma unroll
      for (int dt = 0; dt < 8; ++dt)
#pragma unroll
        for (int r = 0; r < 4; ++r) O[dt][r] *= alr[r];
    }

#pragma unroll
    for (int mt = 0; mt < 4; ++mt)
#pragma unroll
      for (int r = 0; r < 4; ++r) {
        int mloc = mt * 16 + quad * 4 + r;
        Pb[l15 * 64 + (((mloc >> 3) ^ xk) << 3) + (mloc & 7)] = f2h(l2v[mt][r]);
      }
#pragma unroll
    for (int ks2 = 0; ks2 < 2; ++ks2) {
      f16x8 a = ldfrag(Pb + l15 * 64 + (((ks2 * 4 + quad) ^ xk) << 3));
#pragma unroll
      for (int dt = 0; dt < 8; ++dt) {
        f16x8 b = ldfrag(sVt + (dt * 16 + l15) * 64 + (((ks2 * 4 + quad) ^ xk) << 3));
        O[dt] = mfma16(a, b, O[dt]);
      }
    }
  }

  Lacc += __shfl_xor(Lacc, 16);
  Lacc += __shfl_xor(Lacc, 32);

  int plane = p * 2 + s_;
  uint16_t* Op = Opart + (size_t)plane * 2097152;
#pragma unroll
  for (int dt = 0; dt < 8; ++dt)
#pragma unroll
    for (int r = 0; r < 4; ++r)
      Op[(size_t)(qbase + quad * 4 + r) * 1024 + h * 128 + dt * 16 + l15] =
          f2h(O[dt][r]);
  if (lane < 16) {
    int qrow = qbase + lane;
    Mpart[((size_t)plane * 8 + h) * 2048 + qrow] = M;
    Lpart[((size_t)plane * 8 + h) * 2048 + qrow] = Lacc;
  }
}

// ---------------- fused combine + cooperative sim_round2 --------------------
// Phase A: gather masked m-indices (typically 1: the diagonal) into LDS list.
// Phase B: per masked m, all 256 threads compute the 16 (path,head) dots
// cooperatively (thread t: pair=t>>4, dims (t&15)*8..+8). No divergence.
__global__ __launch_bounds__(256) void combine_sim_kernel(
    const uint16_t* __restrict__ Opart, const float* __restrict__ Mpart,
    const float* __restrict__ Lpart, const uint8_t* __restrict__ mask,
    const uint16_t* __restrict__ Qc, const uint16_t* __restrict__ Kc,
    const uint16_t* __restrict__ Qr, const uint16_t* __restrict__ Kr,
    const float* __restrict__ cls_score, const float* __restrict__ fg_score,
    float* __restrict__ out, float* __restrict__ simout) {
  int n = blockIdx.x;
  int t = threadIdx.x;
  __shared__ float sM[2][8], sL[2][8];
  __shared__ float srow[2048];
  __shared__ int mlist[256];
  __shared__ int mcnt;
  __shared__ float pairvals[16];
  __shared__ float psum_s;

  if (t == 0) { mcnt = 0; psum_s = 0.f; }
  if (t < 16) {
    int p = t >> 3, hh = t & 7;
    size_t i1 = ((size_t)(p * 2 + 0) * 8 + hh) * 2048 + n;
    size_t i2 = ((size_t)(p * 2 + 1) * 8 + hh) * 2048 + n;
    float M1 = Mpart[i1], M2 = Mpart[i2];
    float L1 = Lpart[i1], L2 = Lpart[i2];
    float Mx = fmaxf(M1, M2);
    float Lx = L1 * __builtin_amdgcn_exp2f(M1 - Mx) +
               L2 * __builtin_amdgcn_exp2f(M2 - Mx);
    sM[p][hh] = Mx;
    sL[p][hh] = Lx;
  }
#pragma unroll
  for (int i = 0; i < 8; ++i) srow[i * 256 + t] = 0.f;
  __syncthreads();

  // combine partials -> out row n (first 1024 cols)
  {
    int col = t * 4;
    int h = col >> 7;
    float res[4] = {0.f, 0.f, 0.f, 0.f};
#pragma unroll
    for (int p = 0; p < 2; ++p) {
      size_t i1 = ((size_t)(p * 2 + 0) * 8 + h) * 2048 + n;
      size_t i2 = ((size_t)(p * 2 + 1) * 8 + h) * 2048 + n;
      float Mx = sM[p][h];
      float iLx = 0.5f / sL[p][h];
      float f1 = __builtin_amdgcn_exp2f(Mpart[i1] - Mx) * iLx;
      float f2 = __builtin_amdgcn_exp2f(Mpart[i2] - Mx) * iLx;
      const uint16_t* O1 = Opart + (size_t)(p * 2 + 0) * 2097152 + (size_t)n * 1024 + col;
      const uint16_t* O2 = Opart + (size_t)(p * 2 + 1) * 2097152 + (size_t)n * 1024 + col;
      ushort4 a1 = *(const ushort4*)O1;
      ushort4 a2 = *(const ushort4*)O2;
      res[0] += h2f(a1.x) * f1 + h2f(a2.x) * f2;
      res[1] += h2f(a1.y) * f1 + h2f(a2.y) * f2;
      res[2] += h2f(a1.z) * f1 + h2f(a2.z) * f2;
      res[3] += h2f(a1.w) * f1 + h2f(a2.w) * f2;
    }
    float4 r4 = {res[0], res[1], res[2], res[3]};
    *(float4*)(out + (size_t)n * 2048 + col) = r4;
  }

  // Phase A: gather masked indices
  {
    int mbase = t * 8;
    union { unsigned long long v; uint8_t b[8]; } mk;
    mk.v = *(const unsigned long long*)(mask + (size_t)n * 2048 + mbase);
    if (mk.v) {
#pragma unroll
      for (int i = 0; i < 8; ++i)
        if (mk.b[i]) {
          int idx = atomicAdd(&mcnt, 1);
          if (idx < 256) mlist[idx] = mbase + i;
        }
    }
  }
  __syncthreads();
  int cnt = mcnt < 256 ? mcnt : 256;

  // Phase B: cooperative dots per masked m
  int pair = t >> 4;
  int p = pair >> 3, hh = pair & 7;
  int dchunk = (t & 15) * 8;
  const float* sc = p ? fg_score : cls_score;
  float thr = sc[n] - 0.1f;
  f16x8 qv = ldfrag(((p ? Qr : Qc) + ((size_t)hh * 2048 + n) * 128) + dchunk);
  const uint16_t* Kbase = (p ? Kr : Kc) + (size_t)hh * 2048 * 128 + dchunk;
  float iL = 1.0f / sL[p][hh];
  float Mme = sM[p][hh];

  for (int ii = 0; ii < cnt; ++ii) {
    int m = mlist[ii];
    f16x8 kv = ldfrag(Kbase + (size_t)m * 128);
    float d = 0.f;
#pragma unroll
    for (int j = 0; j < 8; ++j) d += (float)qv[j] * (float)kv[j];
    d += __shfl_xor(d, 1);
    d += __shfl_xor(d, 2);
    d += __shfl_xor(d, 4);
    d += __shfl_xor(d, 8);
    if ((t & 15) == 0) {
      float scm = sc[m];
      float logit = (scm > thr) ? d * (scm * SC25) : 0.0f;
      pairvals[pair] = __builtin_amdgcn_exp2f(logit - Mme) * iL;
    }
    __syncthreads();
    if (t == 0) {
      float s = 0.f;
#pragma unroll
      for (int k = 0; k < 16; ++k) s += pairvals[k];
      float val = __builtin_amdgcn_exp2f(s * (K2E / 16.0f));  // e^(s/16)
      srow[m] = val;
      psum_s += val;
    }
    __syncthreads();
  }

  float inv = 1.0f / psum_s;
  int mbase = t * 8;
  float4 r0 = {srow[mbase] * inv, srow[mbase + 1] * inv,
               srow[mbase + 2] * inv, srow[mbase + 3] * inv};
  float4 r1 = {srow[mbase + 4] * inv, srow[mbase + 5] * inv,
               srow[mbase + 6] * inv, srow[mbase + 7] * inv};
  *(float4*)(simout + (size_t)n * 2048 + mbase) = r0;
  *(float4*)(simout + (size_t)n * 2048 + mbase + 4) = r1;
}

// ---------------- host launch ------------------------------------------------
extern "C" void kernel_launch(void* const* d_in, const int* in_sizes, int n_in,
                              void* d_out, int out_size, void* d_ws, size_t ws_size,
                              hipStream_t stream) {
  const float* x_cls = (const float*)d_in[0];
  const float* x_reg = (const float*)d_in[1];
  const float* cls_score = (const float*)d_in[2];
  const float* fg_score = (const float*)d_in[3];
  const float* W_cls = (const float*)d_in[4];
  const float* W_reg = (const float*)d_in[5];
  float* out = (float*)d_out;
  char* ws = (char*)d_ws;

  const size_t OFF_XC   = 0;
  const size_t OFF_XR   = OFF_XC + 4194304;
  const size_t OFF_WTC  = OFF_XR + 4194304;
  const size_t OFF_WTR  = OFF_WTC + 6291456;
  const size_t OFF_QC   = OFF_WTR + 4194304;
  const size_t OFF_KC   = OFF_QC + 4194304;
  const size_t OFF_QR   = OFF_KC + 4194304;
  const size_t OFF_KR   = OFF_QR + 4194304;
  const size_t OFF_VT   = OFF_KR + 4194304;
  const size_t OFF_VCAT = OFF_VT + 4194304;
  const size_t OFF_OP   = OFF_VCAT + 4194304;   // 16 MB
  const size_t OFF_MP   = OFF_OP + 16777216;    // 256 KB
  const size_t OFF_LP   = OFF_MP + 262144;      // 256 KB
  const size_t OFF_MASK = OFF_LP + 262144;      // 4 MB

  uint16_t* xc_b = (uint16_t*)(ws + OFF_XC);
  uint16_t* xr_b = (uint16_t*)(ws + OFF_XR);
  uint16_t* Wtc  = (uint16_t*)(ws + OFF_WTC);
  uint16_t* Wtr  = (uint16_t*)(ws + OFF_WTR);
  uint16_t* Qc   = (uint16_t*)(ws + OFF_QC);
  uint16_t* Kc   = (uint16_t*)(ws + OFF_KC);
  uint16_t* Qr   = (uint16_t*)(ws + OFF_QR);
  uint16_t* Kr   = (uint16_t*)(ws + OFF_KR);
  uint16_t* Vt   = (uint16_t*)(ws + OFF_VT);
  uint16_t* Vcat = (uint16_t*)(ws + OFF_VCAT);
  uint16_t* Opart = (uint16_t*)(ws + OFF_OP);
  float* Mpart   = (float*)(ws + OFF_MP);
  float* Lpart   = (float*)(ws + OFF_LP);
  uint8_t* mask  = (uint8_t*)(ws + OFF_MASK);

  prep_kernel<<<3328, 256, 0, stream>>>(x_cls, x_reg, W_cls, W_reg,
                                        xc_b, xr_b, Wtc, Wtr);
  gemm_qkv_norm_kernel<<<dim3(16, 40), 256, 0, stream>>>(
      xc_b, Wtc, xr_b, Wtr, Qc, Kc, Qr, Kr, Vt, Vcat, out);
  gemm_mask_kernel<<<dim3(16, 16), 256, 0, stream>>>(Vcat, mask);
  attn_kernel<<<1024, 256, 0, stream>>>(Qc, Kc, Qr, Kr, Vt, cls_score, fg_score,
                                        Opart, Mpart, Lpart);
  combine_sim_kernel<<<2048, 256, 0, stream>>>(Opart, Mpart, Lpart, mask,
                                               Qc, Kc, Qr, Kr, cls_score,
                                               fg_score, out, out + 4194304);
}